// Round 1
// baseline (62232.538 us; speedup 1.0000x reference)
//
#include <hip/hip_runtime.h>

#define SEQ 8192
#define H 1024

// ---------------------------------------------------------------------------
// Projection GEMM (NT): C[i][j] = bias[j] + sum_k A[i][k]*B[j][k]
// A=[8192,1024] row-major, B=[1024,1024] row-major. Tile 64x64, KC=32,
// 256 threads, 4x4 microtile/thread. LDS tiles stored [k][i] (LDT=68 pad)
// so fragments read as ds_read_b128 (a-frag broadcast, b-frag 2-way=free).
// ---------------------------------------------------------------------------
#define KC 32
#define LDT 68

__global__ __launch_bounds__(256) void proj_gemm(
    const float* __restrict__ A,
    const float* __restrict__ B0, const float* __restrict__ b0, float* __restrict__ C0,
    const float* __restrict__ B1, const float* __restrict__ b1, float* __restrict__ C1,
    const float* __restrict__ B2, const float* __restrict__ b2, float* __restrict__ C2)
{
    __shared__ __align__(16) float As[KC * LDT];
    __shared__ __align__(16) float Bs[KC * LDT];

    const float* Bm; const float* bias; float* C;
    if (blockIdx.z == 0)      { Bm = B0; bias = b0; C = C0; }
    else if (blockIdx.z == 1) { Bm = B1; bias = b1; C = C1; }
    else                      { Bm = B2; bias = b2; C = C2; }

    const int j0 = blockIdx.x * 64;
    const int i0 = blockIdx.y * 64;
    const int tid = threadIdx.x;
    const int tx = tid & 15, ty = tid >> 4;
    const int lrow = tid >> 3;   // 0..31
    const int lkq  = tid & 7;    // 0..7  -> k = 4*lkq

    float acc[4][4];
#pragma unroll
    for (int r = 0; r < 4; r++)
#pragma unroll
        for (int c = 0; c < 4; c++) acc[r][c] = 0.f;

    for (int k0 = 0; k0 < H; k0 += KC) {
#pragma unroll
        for (int half = 0; half < 2; half++) {
            const int row = lrow + half * 32;
            float4 a = *(const float4*)&A[(size_t)(i0 + row) * H + k0 + 4 * lkq];
            As[(4 * lkq + 0) * LDT + row] = a.x;
            As[(4 * lkq + 1) * LDT + row] = a.y;
            As[(4 * lkq + 2) * LDT + row] = a.z;
            As[(4 * lkq + 3) * LDT + row] = a.w;
            float4 b = *(const float4*)&Bm[(size_t)(j0 + row) * H + k0 + 4 * lkq];
            Bs[(4 * lkq + 0) * LDT + row] = b.x;
            Bs[(4 * lkq + 1) * LDT + row] = b.y;
            Bs[(4 * lkq + 2) * LDT + row] = b.z;
            Bs[(4 * lkq + 3) * LDT + row] = b.w;
        }
        __syncthreads();
#pragma unroll
        for (int k = 0; k < KC; k++) {
            float4 a4 = *(const float4*)&As[k * LDT + ty * 4];
            float4 b4 = *(const float4*)&Bs[k * LDT + tx * 4];
            acc[0][0] += a4.x * b4.x; acc[0][1] += a4.x * b4.y;
            acc[0][2] += a4.x * b4.z; acc[0][3] += a4.x * b4.w;
            acc[1][0] += a4.y * b4.x; acc[1][1] += a4.y * b4.y;
            acc[1][2] += a4.y * b4.z; acc[1][3] += a4.y * b4.w;
            acc[2][0] += a4.z * b4.x; acc[2][1] += a4.z * b4.y;
            acc[2][2] += a4.z * b4.z; acc[2][3] += a4.z * b4.w;
            acc[3][0] += a4.w * b4.x; acc[3][1] += a4.w * b4.y;
            acc[3][2] += a4.w * b4.z; acc[3][3] += a4.w * b4.w;
        }
        __syncthreads();
    }

    float4 bi = *(const float4*)&bias[j0 + tx * 4];
#pragma unroll
    for (int r = 0; r < 4; r++) {
        float4 o;
        o.x = acc[r][0] + bi.x; o.y = acc[r][1] + bi.y;
        o.z = acc[r][2] + bi.z; o.w = acc[r][3] + bi.w;
        *(float4*)&C[(size_t)(i0 + ty * 4 + r) * H + j0 + tx * 4] = o;
    }
}

// ---------------------------------------------------------------------------
// Sequential GRU scan. 128 blocks x 512 threads (8 waves). Wave w of block b
// owns hidden unit j = b*8+w; its 3 weight rows (Wu/Wr/W[j][:]) live in
// registers as 4 float4 per matrix (lane l covers k in {256m+4l..256m+4l+3}).
// Per step: poll per-block flags (agent-scope relaxed atomics), acquire fence,
// vectorized h load, 48 FMA/lane, 3 wave reductions, lane0 does sigmoids and
// publishes h_new; block publishes its flag with an agent release store.
// Double-buffered h; flag[b] = #steps completed by block b (max skew 1).
// ---------------------------------------------------------------------------
__global__ __launch_bounds__(512) void gru_scan(
    const float* __restrict__ xu, const float* __restrict__ xr, const float* __restrict__ xc,
    const float* __restrict__ Wu, const float* __restrict__ Wr, const float* __restrict__ W,
    float* __restrict__ hbuf,   // 2*H floats (zeroed)
    int* __restrict__ flags,    // 128 ints (zeroed)
    float* __restrict__ out)    // d_out: [H h_final][SEQ*H outputs]
{
    const int bid  = blockIdx.x;     // 0..127
    const int tid  = threadIdx.x;    // 0..511
    const int wid  = tid >> 6;       // 0..7
    const int lane = tid & 63;
    const int j    = bid * 8 + wid;  // hidden unit owned by this wave

    float4 wu[4], wr[4], wc[4];
    {
        const float4* pu = (const float4*)(Wu + (size_t)j * H);
        const float4* pr = (const float4*)(Wr + (size_t)j * H);
        const float4* pw = (const float4*)(W  + (size_t)j * H);
#pragma unroll
        for (int m = 0; m < 4; m++) {
            wu[m] = pu[m * 64 + lane];
            wr[m] = pr[m * 64 + lane];
            wc[m] = pw[m * 64 + lane];
        }
    }
    float* outs = out + H;

    for (int t = 0; t < SEQ; t++) {
        const float* hc = hbuf + (t & 1) * H;
        float*       hn = hbuf + ((t + 1) & 1) * H;

        // prefetch this step's input projections (written by prior kernel)
        float axu = 0.f, axr = 0.f, axc = 0.f;
        if (lane == 0) {
            axu = xu[(size_t)t * H + j];
            axr = xr[(size_t)t * H + j];
            axc = xc[(size_t)t * H + j];
        }

        if (wid == 0) {
            for (;;) {
                int f0 = __hip_atomic_load(&flags[lane],      __ATOMIC_RELAXED, __HIP_MEMORY_SCOPE_AGENT);
                int f1 = __hip_atomic_load(&flags[lane + 64], __ATOMIC_RELAXED, __HIP_MEMORY_SCOPE_AGENT);
                if (__all(f0 >= t && f1 >= t)) break;
            }
            __threadfence();   // acquire: invalidate stale L1/L2 before h loads
        }
        __syncthreads();

        const float4* h4 = (const float4*)hc;
        float au = 0.f, ar = 0.f, aw = 0.f;
#pragma unroll
        for (int m = 0; m < 4; m++) {
            float4 h = h4[m * 64 + lane];
            au += wu[m].x * h.x + wu[m].y * h.y + wu[m].z * h.z + wu[m].w * h.w;
            ar += wr[m].x * h.x + wr[m].y * h.y + wr[m].z * h.z + wr[m].w * h.w;
            aw += wc[m].x * h.x + wc[m].y * h.y + wc[m].z * h.z + wc[m].w * h.w;
        }
        float hold = 0.f;
        if (lane == 0) hold = hc[j];

#pragma unroll
        for (int off = 32; off > 0; off >>= 1) {
            au += __shfl_xor(au, off, 64);
            ar += __shfl_xor(ar, off, 64);
            aw += __shfl_xor(aw, off, 64);
        }

        if (lane == 0) {
            float u    = 1.f / (1.f + __expf(-(axu + au)));
            float r    = 1.f / (1.f + __expf(-(axr + ar)));
            float cand = 1.f / (1.f + __expf(-(axc + r * aw)));
            float hnew = u * hold + (1.f - u) * cand;
            hn[j] = hnew;                       // plain store; flushed by release below
            outs[(size_t)t * H + j] = hnew;
            if (t == SEQ - 1) out[j] = hnew;    // h_final
        }
        __syncthreads();   // drains each wave's vmcnt -> h stores are in this XCD's L2
        if (tid == 0)
            __hip_atomic_store(&flags[bid], t + 1, __ATOMIC_RELEASE, __HIP_MEMORY_SCOPE_AGENT);
    }
}

// ---------------------------------------------------------------------------
extern "C" void kernel_launch(void* const* d_in, const int* in_sizes, int n_in,
                              void* d_out, int out_size, void* d_ws, size_t ws_size,
                              hipStream_t stream) {
    const float* x  = (const float*)d_in[0];
    const float* Uu = (const float*)d_in[1];
    const float* Wu = (const float*)d_in[2];
    const float* Bu = (const float*)d_in[3];
    const float* Ur = (const float*)d_in[4];
    const float* Wr = (const float*)d_in[5];
    const float* Br = (const float*)d_in[6];
    const float* U  = (const float*)d_in[7];
    const float* W  = (const float*)d_in[8];
    const float* B  = (const float*)d_in[9];

    char* ws = (char*)d_ws;
    const size_t MAT = (size_t)SEQ * H * sizeof(float);  // 32 MB
    float* xu = (float*)(ws);
    float* xr = (float*)(ws + MAT);
    float* xc = (float*)(ws + 2 * MAT);
    float* hb = (float*)(ws + 3 * MAT);                   // 2*H floats
    int* flags = (int*)(ws + 3 * MAT + 2 * H * sizeof(float));

    // zero h0 + flags (ws is re-poisoned 0xAA before every timed launch)
    hipMemsetAsync(hb, 0, 2 * H * sizeof(float) + 128 * sizeof(int), stream);

    dim3 g(H / 64, SEQ / 64, 3);
    proj_gemm<<<g, 256, 0, stream>>>(x, Uu, Bu, xu, Ur, Br, xr, U, B, xc);

    gru_scan<<<128, 512, 0, stream>>>(xu, xr, xc, Wu, Wr, W, hb, flags, (float*)d_out);
}

// Round 3
// 39288.672 us; speedup vs baseline: 1.5840x; 1.5840x over previous
//
#include <hip/hip_runtime.h>

#define SEQ 8192
#define H 1024

// ---------------------------------------------------------------------------
// Projection GEMM (NT): C[i][j] = bias[j] + sum_k A[i][k]*B[j][k]
// (unchanged from R1 — not the bottleneck)
// ---------------------------------------------------------------------------
#define KC 32
#define LDT 68

__global__ __launch_bounds__(256) void proj_gemm(
    const float* __restrict__ A,
    const float* __restrict__ B0, const float* __restrict__ b0, float* __restrict__ C0,
    const float* __restrict__ B1, const float* __restrict__ b1, float* __restrict__ C1,
    const float* __restrict__ B2, const float* __restrict__ b2, float* __restrict__ C2)
{
    __shared__ __align__(16) float As[KC * LDT];
    __shared__ __align__(16) float Bs[KC * LDT];

    const float* Bm; const float* bias; float* C;
    if (blockIdx.z == 0)      { Bm = B0; bias = b0; C = C0; }
    else if (blockIdx.z == 1) { Bm = B1; bias = b1; C = C1; }
    else                      { Bm = B2; bias = b2; C = C2; }

    const int j0 = blockIdx.x * 64;
    const int i0 = blockIdx.y * 64;
    const int tid = threadIdx.x;
    const int tx = tid & 15, ty = tid >> 4;
    const int lrow = tid >> 3;
    const int lkq  = tid & 7;

    float acc[4][4];
#pragma unroll
    for (int r = 0; r < 4; r++)
#pragma unroll
        for (int c = 0; c < 4; c++) acc[r][c] = 0.f;

    for (int k0 = 0; k0 < H; k0 += KC) {
#pragma unroll
        for (int half = 0; half < 2; half++) {
            const int row = lrow + half * 32;
            float4 a = *(const float4*)&A[(size_t)(i0 + row) * H + k0 + 4 * lkq];
            As[(4 * lkq + 0) * LDT + row] = a.x;
            As[(4 * lkq + 1) * LDT + row] = a.y;
            As[(4 * lkq + 2) * LDT + row] = a.z;
            As[(4 * lkq + 3) * LDT + row] = a.w;
            float4 b = *(const float4*)&Bm[(size_t)(j0 + row) * H + k0 + 4 * lkq];
            Bs[(4 * lkq + 0) * LDT + row] = b.x;
            Bs[(4 * lkq + 1) * LDT + row] = b.y;
            Bs[(4 * lkq + 2) * LDT + row] = b.z;
            Bs[(4 * lkq + 3) * LDT + row] = b.w;
        }
        __syncthreads();
#pragma unroll
        for (int k = 0; k < KC; k++) {
            float4 a4 = *(const float4*)&As[k * LDT + ty * 4];
            float4 b4 = *(const float4*)&Bs[k * LDT + tx * 4];
            acc[0][0] += a4.x * b4.x; acc[0][1] += a4.x * b4.y;
            acc[0][2] += a4.x * b4.z; acc[0][3] += a4.x * b4.w;
            acc[1][0] += a4.y * b4.x; acc[1][1] += a4.y * b4.y;
            acc[1][2] += a4.y * b4.z; acc[1][3] += a4.y * b4.w;
            acc[2][0] += a4.z * b4.x; acc[2][1] += a4.z * b4.y;
            acc[2][2] += a4.z * b4.z; acc[2][3] += a4.z * b4.w;
            acc[3][0] += a4.w * b4.x; acc[3][1] += a4.w * b4.y;
            acc[3][2] += a4.w * b4.z; acc[3][3] += a4.w * b4.w;
        }
        __syncthreads();
    }

    float4 bi = *(const float4*)&bias[j0 + tx * 4];
#pragma unroll
    for (int r = 0; r < 4; r++) {
        float4 o;
        o.x = acc[r][0] + bi.x; o.y = acc[r][1] + bi.y;
        o.z = acc[r][2] + bi.z; o.w = acc[r][3] + bi.w;
        *(float4*)&C[(size_t)(i0 + ty * 4 + r) * H + j0 + tx * 4] = o;
    }
}

// ---------------------------------------------------------------------------
// Sequential GRU scan, v2: no cache-maintenance fences. h and flags live at
// the coherence point via sc0+sc1 (L1+L2 bypass) loads/stores; ordering via
// s_waitcnt vmcnt(0) (write-through stores are visible once acked) plus the
// drain __syncthreads already performs. wave0 stages h into LDS once/block.
// 128 blocks x 512 threads; wave w of block b owns unit j=b*8+w; weight rows
// in registers (12 float4/lane); h_old kept in a register by lane0.
// ---------------------------------------------------------------------------
__global__ __launch_bounds__(512, 2) void gru_scan(
    const float* __restrict__ xu, const float* __restrict__ xr, const float* __restrict__ xc,
    const float* __restrict__ Wu, const float* __restrict__ Wr, const float* __restrict__ W,
    float* __restrict__ hbuf,   // 2*H floats (zeroed)
    int* __restrict__ flags,    // 128 ints (zeroed)
    float* __restrict__ out)    // d_out: [H h_final][SEQ*H outputs]
{
    __shared__ __align__(16) float hs[H];

    const int bid  = blockIdx.x;     // 0..127
    const int tid  = threadIdx.x;    // 0..511
    const int wid  = tid >> 6;       // 0..7
    const int lane = tid & 63;
    const int j    = bid * 8 + wid;  // hidden unit owned by this wave

    // weight fragments: lane covers k = m*256 + 4*lane .. +3  (float4 idx m*64+lane)
    float4 wu[4], wr[4], wc[4];
    {
        const float4* pu = (const float4*)(Wu + (size_t)j * H);
        const float4* pr = (const float4*)(Wr + (size_t)j * H);
        const float4* pw = (const float4*)(W  + (size_t)j * H);
#pragma unroll
        for (int m = 0; m < 4; m++) {
            wu[m] = pu[m * 64 + lane];
            wr[m] = pr[m * 64 + lane];
            wc[m] = pw[m * 64 + lane];
        }
    }
    float* outs = out + H;
    float hprev = 0.f;               // lane0: previous h[j]

    for (int t = 0; t < SEQ; t++) {
        float* hn = hbuf + ((t + 1) & 1) * H;

        // prefetch this step's input projections (cached loads, overlap poll)
        float axu = 0.f, axr = 0.f, axc = 0.f;
        if (lane == 0) {
            axu = xu[(size_t)t * H + j];
            axr = xr[(size_t)t * H + j];
            axc = xc[(size_t)t * H + j];
        }

        if (wid == 0) {
            // poll 128 flags with coherence-point loads (no cache invalidate)
            const int* p0 = flags + lane;
            const int* p1 = flags + lane + 64;
            for (;;) {
                int f0, f1;
                asm volatile(
                    "global_load_dword %0, %2, off sc0 sc1\n\t"
                    "global_load_dword %1, %3, off sc0 sc1\n\t"
                    "s_waitcnt vmcnt(0)"
                    : "=&v"(f0), "=&v"(f1)
                    : "v"(p0), "v"(p1)
                    : "memory");
                if (__all(f0 >= t && f1 >= t)) break;
                asm volatile("s_sleep 1");
            }
            // load h (4 KB) from coherence point, stage into LDS
            const float* hc = hbuf + (t & 1) * H;
            const float4* hp = (const float4*)hc + lane;   // +offset m*1024 B
            float4 h0, h1, h2, h3;
            asm volatile(
                "global_load_dwordx4 %0, %4, off sc0 sc1\n\t"
                "global_load_dwordx4 %1, %4, off offset:1024 sc0 sc1\n\t"
                "global_load_dwordx4 %2, %4, off offset:2048 sc0 sc1\n\t"
                "global_load_dwordx4 %3, %4, off offset:3072 sc0 sc1\n\t"
                "s_waitcnt vmcnt(0)"
                : "=&v"(h0), "=&v"(h1), "=&v"(h2), "=&v"(h3)
                : "v"(hp)
                : "memory");
            float4* hs4 = (float4*)hs;
            hs4[lane]       = h0;
            hs4[64  + lane] = h1;
            hs4[128 + lane] = h2;
            hs4[192 + lane] = h3;
        }
        __syncthreads();

        const float4* hsl = (const float4*)hs;
        float au = 0.f, ar = 0.f, aw = 0.f;
#pragma unroll
        for (int m = 0; m < 4; m++) {
            float4 h = hsl[m * 64 + lane];
            au += wu[m].x * h.x + wu[m].y * h.y + wu[m].z * h.z + wu[m].w * h.w;
            ar += wr[m].x * h.x + wr[m].y * h.y + wr[m].z * h.z + wr[m].w * h.w;
            aw += wc[m].x * h.x + wc[m].y * h.y + wc[m].z * h.z + wc[m].w * h.w;
        }

#pragma unroll
        for (int off = 32; off > 0; off >>= 1) {
            au += __shfl_xor(au, off, 64);
            ar += __shfl_xor(ar, off, 64);
            aw += __shfl_xor(aw, off, 64);
        }

        if (lane == 0) {
            float u    = 1.f / (1.f + __expf(-(axu + au)));
            float r    = 1.f / (1.f + __expf(-(axr + ar)));
            float cand = 1.f / (1.f + __expf(-(axc + r * aw)));
            float hnew = u * hprev + (1.f - u) * cand;
            hprev = hnew;
            // publish h_new at the coherence point (bypass L1+L2)
            asm volatile("global_store_dword %0, %1, off sc0 sc1"
                         :: "v"(hn + j), "v"(hnew) : "memory");
            outs[(size_t)t * H + j] = hnew;       // plain cached store
            if (t == SEQ - 1) out[j] = hnew;      // h_final
        }
        __syncthreads();   // drains every wave's vmcnt -> h stores acked at L3
        if (tid == 0) {
            int fv = t + 1;
            int* fp = flags + bid;
            asm volatile(
                "s_waitcnt vmcnt(0)\n\t"
                "global_store_dword %0, %1, off sc0 sc1"
                :: "v"(fp), "v"(fv) : "memory");
        }
    }
}

// ---------------------------------------------------------------------------
extern "C" void kernel_launch(void* const* d_in, const int* in_sizes, int n_in,
                              void* d_out, int out_size, void* d_ws, size_t ws_size,
                              hipStream_t stream) {
    const float* x  = (const float*)d_in[0];
    const float* Uu = (const float*)d_in[1];
    const float* Wu = (const float*)d_in[2];
    const float* Bu = (const float*)d_in[3];
    const float* Ur = (const float*)d_in[4];
    const float* Wr = (const float*)d_in[5];
    const float* Br = (const float*)d_in[6];
    const float* U  = (const float*)d_in[7];
    const float* W  = (const float*)d_in[8];
    const float* B  = (const float*)d_in[9];

    char* ws = (char*)d_ws;
    const size_t MAT = (size_t)SEQ * H * sizeof(float);  // 32 MB
    float* xu = (float*)(ws);
    float* xr = (float*)(ws + MAT);
    float* xc = (float*)(ws + 2 * MAT);
    float* hb = (float*)(ws + 3 * MAT);                   // 2*H floats
    int* flags = (int*)(ws + 3 * MAT + 2 * H * sizeof(float));

    hipMemsetAsync(hb, 0, 2 * H * sizeof(float) + 128 * sizeof(int), stream);

    dim3 g(H / 64, SEQ / 64, 3);
    proj_gemm<<<g, 256, 0, stream>>>(x, Uu, Bu, xu, Ur, Br, xr, U, B, xc);

    gru_scan<<<128, 512, 0, stream>>>(xu, xr, xc, Wu, Wr, W, hb, flags, (float*)d_out);
}

// Round 4
// 20030.334 us; speedup vs baseline: 3.1069x; 1.9615x over previous
//
#include <hip/hip_runtime.h>

#define SEQ 8192
#define H 1024

// ---------------------------------------------------------------------------
// Projection GEMM (NT): C[i][j] = bias[j] + sum_k A[i][k]*B[j][k]
// (unchanged — ~1 ms, not the bottleneck)
// ---------------------------------------------------------------------------
#define KC 32
#define LDT 68

__global__ __launch_bounds__(256) void proj_gemm(
    const float* __restrict__ A,
    const float* __restrict__ B0, const float* __restrict__ b0, float* __restrict__ C0,
    const float* __restrict__ B1, const float* __restrict__ b1, float* __restrict__ C1,
    const float* __restrict__ B2, const float* __restrict__ b2, float* __restrict__ C2)
{
    __shared__ __align__(16) float As[KC * LDT];
    __shared__ __align__(16) float Bs[KC * LDT];

    const float* Bm; const float* bias; float* C;
    if (blockIdx.z == 0)      { Bm = B0; bias = b0; C = C0; }
    else if (blockIdx.z == 1) { Bm = B1; bias = b1; C = C1; }
    else                      { Bm = B2; bias = b2; C = C2; }

    const int j0 = blockIdx.x * 64;
    const int i0 = blockIdx.y * 64;
    const int tid = threadIdx.x;
    const int tx = tid & 15, ty = tid >> 4;
    const int lrow = tid >> 3;
    const int lkq  = tid & 7;

    float acc[4][4];
#pragma unroll
    for (int r = 0; r < 4; r++)
#pragma unroll
        for (int c = 0; c < 4; c++) acc[r][c] = 0.f;

    for (int k0 = 0; k0 < H; k0 += KC) {
#pragma unroll
        for (int half = 0; half < 2; half++) {
            const int row = lrow + half * 32;
            float4 a = *(const float4*)&A[(size_t)(i0 + row) * H + k0 + 4 * lkq];
            As[(4 * lkq + 0) * LDT + row] = a.x;
            As[(4 * lkq + 1) * LDT + row] = a.y;
            As[(4 * lkq + 2) * LDT + row] = a.z;
            As[(4 * lkq + 3) * LDT + row] = a.w;
            float4 b = *(const float4*)&Bm[(size_t)(j0 + row) * H + k0 + 4 * lkq];
            Bs[(4 * lkq + 0) * LDT + row] = b.x;
            Bs[(4 * lkq + 1) * LDT + row] = b.y;
            Bs[(4 * lkq + 2) * LDT + row] = b.z;
            Bs[(4 * lkq + 3) * LDT + row] = b.w;
        }
        __syncthreads();
#pragma unroll
        for (int k = 0; k < KC; k++) {
            float4 a4 = *(const float4*)&As[k * LDT + ty * 4];
            float4 b4 = *(const float4*)&Bs[k * LDT + tx * 4];
            acc[0][0] += a4.x * b4.x; acc[0][1] += a4.x * b4.y;
            acc[0][2] += a4.x * b4.z; acc[0][3] += a4.x * b4.w;
            acc[1][0] += a4.y * b4.x; acc[1][1] += a4.y * b4.y;
            acc[1][2] += a4.y * b4.z; acc[1][3] += a4.y * b4.w;
            acc[2][0] += a4.z * b4.x; acc[2][1] += a4.z * b4.y;
            acc[2][2] += a4.z * b4.z; acc[2][3] += a4.z * b4.w;
            acc[3][0] += a4.w * b4.x; acc[3][1] += a4.w * b4.y;
            acc[3][2] += a4.w * b4.z; acc[3][3] += a4.w * b4.w;
        }
        __syncthreads();
    }

    float4 bi = *(const float4*)&bias[j0 + tx * 4];
#pragma unroll
    for (int r = 0; r < 4; r++) {
        float4 o;
        o.x = acc[r][0] + bi.x; o.y = acc[r][1] + bi.y;
        o.z = acc[r][2] + bi.z; o.w = acc[r][3] + bi.w;
        *(float4*)&C[(size_t)(i0 + ty * 4 + r) * H + j0 + tx * 4] = o;
    }
}

// ---------------------------------------------------------------------------
// GRU scan v3: data-as-flag. Each unit's h is published as an 8B (value,tag)
// pair with ONE system-scope relaxed store; consumers poll the tagged slots
// directly (arrival proof travels with the data -> single round trip, no
// producer-side vmcnt drain, no separate flag, no cache maintenance).
// Ring of 8 step-slots: per-step block barriers bound inter-block skew far
// below 8, so WAR on a slot is impossible; stale tags (incl. 0xAA poison)
// never match the expected step tag, so NO initialization is needed.
// 64 blocks x 1024 threads (16 waves); wave w owns unit j = bid*16 + w;
// weight rows in registers (12 float4/lane). Wave w polls units w*64..+63
// and stages them to LDS; barrier; 48 FMA/lane; 3 shuffle reductions;
// lane0 applies gates and publishes the tagged pair for step t+1.
// ---------------------------------------------------------------------------
#define RING 8

__global__ __launch_bounds__(1024, 1) void gru_scan(
    const float* __restrict__ xu, const float* __restrict__ xr, const float* __restrict__ xc,
    const float* __restrict__ Wu, const float* __restrict__ Wr, const float* __restrict__ W,
    unsigned long long* __restrict__ th,  // RING*H tagged pairs (no init needed)
    float* __restrict__ out)              // d_out: [H h_final][SEQ*H outputs]
{
    __shared__ __align__(16) float hs[H];

    const int bid  = blockIdx.x;     // 0..63
    const int tid  = threadIdx.x;    // 0..1023
    const int wid  = tid >> 6;       // 0..15
    const int lane = tid & 63;
    const int j    = bid * 16 + wid; // hidden unit owned by this wave

    // weight fragments: float4 m covers k = m*256 + 4*lane .. +3
    float4 wu[4], wr[4], wc[4];
    {
        const float4* pu = (const float4*)(Wu + (size_t)j * H);
        const float4* pr = (const float4*)(Wr + (size_t)j * H);
        const float4* pw = (const float4*)(W  + (size_t)j * H);
#pragma unroll
        for (int m = 0; m < 4; m++) {
            wu[m] = pu[m * 64 + lane];
            wr[m] = pr[m * 64 + lane];
            wc[m] = pw[m * 64 + lane];
        }
    }
    float* outs = out + H;
    float hprev = 0.f;               // lane0: previous h[j]

    for (int t = 0; t < SEQ; t++) {
        // prefetch this step's input projections (cached; 64B line per block)
        float axu = 0.f, axr = 0.f, axc = 0.f;
        if (lane == 0) {
            axu = xu[(size_t)t * H + j];
            axr = xr[(size_t)t * H + j];
            axc = xc[(size_t)t * H + j];
        }

        if (t == 0) {
            hs[wid * 64 + lane] = 0.f;   // h0 = 0, nothing to poll
        } else {
            // wave w polls units w*64..w*64+63 of slot (t & 7) for tag t
            const unsigned long long* p = th + (size_t)(t & (RING - 1)) * H
                                             + wid * 64 + lane;
            unsigned long long v;
            for (;;) {
                v = __hip_atomic_load(p, __ATOMIC_RELAXED, __HIP_MEMORY_SCOPE_SYSTEM);
                if (__all((int)(v >> 32) == t)) break;
            }
            hs[wid * 64 + lane] = __uint_as_float((unsigned)v);
        }
        __syncthreads();

        const float4* hsl = (const float4*)hs;
        float au = 0.f, ar = 0.f, aw = 0.f;
#pragma unroll
        for (int m = 0; m < 4; m++) {
            float4 h = hsl[m * 64 + lane];
            au += wu[m].x * h.x + wu[m].y * h.y + wu[m].z * h.z + wu[m].w * h.w;
            ar += wr[m].x * h.x + wr[m].y * h.y + wr[m].z * h.z + wr[m].w * h.w;
            aw += wc[m].x * h.x + wc[m].y * h.y + wc[m].z * h.z + wc[m].w * h.w;
        }

#pragma unroll
        for (int off = 32; off > 0; off >>= 1) {
            au += __shfl_xor(au, off, 64);
            ar += __shfl_xor(ar, off, 64);
            aw += __shfl_xor(aw, off, 64);
        }

        if (lane == 0) {
            float u    = 1.f / (1.f + __expf(-(axu + au)));
            float r    = 1.f / (1.f + __expf(-(axr + ar)));
            float cand = 1.f / (1.f + __expf(-(axc + r * aw)));
            float hnew = u * hprev + (1.f - u) * cand;
            hprev = hnew;
            // publish (value, tag=t+1) in ONE 8B system-scope store
            unsigned long long pkt =
                ((unsigned long long)(unsigned)(t + 1) << 32) |
                (unsigned long long)__float_as_uint(hnew);
            unsigned long long* q = th + (size_t)((t + 1) & (RING - 1)) * H + j;
            __hip_atomic_store(q, pkt, __ATOMIC_RELAXED, __HIP_MEMORY_SCOPE_SYSTEM);
            outs[(size_t)t * H + j] = hnew;       // plain cached store
            if (t == SEQ - 1) out[j] = hnew;      // h_final
        }
        __syncthreads();   // protects hs reuse; keeps block skew < RING
    }
}

// ---------------------------------------------------------------------------
extern "C" void kernel_launch(void* const* d_in, const int* in_sizes, int n_in,
                              void* d_out, int out_size, void* d_ws, size_t ws_size,
                              hipStream_t stream) {
    const float* x  = (const float*)d_in[0];
    const float* Uu = (const float*)d_in[1];
    const float* Wu = (const float*)d_in[2];
    const float* Bu = (const float*)d_in[3];
    const float* Ur = (const float*)d_in[4];
    const float* Wr = (const float*)d_in[5];
    const float* Br = (const float*)d_in[6];
    const float* U  = (const float*)d_in[7];
    const float* W  = (const float*)d_in[8];
    const float* B  = (const float*)d_in[9];

    char* ws = (char*)d_ws;
    const size_t MAT = (size_t)SEQ * H * sizeof(float);  // 32 MB
    float* xu = (float*)(ws);
    float* xr = (float*)(ws + MAT);
    float* xc = (float*)(ws + 2 * MAT);
    unsigned long long* th = (unsigned long long*)(ws + 3 * MAT);  // 64 KB ring

    dim3 g(H / 64, SEQ / 64, 3);
    proj_gemm<<<g, 256, 0, stream>>>(x, Uu, Bu, xu, Ur, Br, xr, U, B, xc);

    gru_scan<<<64, 1024, 0, stream>>>(xu, xr, xc, Wu, Wr, W, th, (float*)d_out);
}